// Round 1
// baseline (346.534 us; speedup 1.0000x reference)
//
#include <hip/hip_runtime.h>
#include <hip/hip_cooperative_groups.h>
#include <math.h>

namespace cg = cooperative_groups;

#define D 2048
#define F 256
#define ALPHA 0.005f
#define STOPTHR 0.005f
#define EPSV 1e-16f
#define ROWS_PER_BLK 8
#define NBLK (D / ROWS_PER_BLK)  // 256 blocks, 1 per CU

// ---------------- row stats: sq[i] = ||theta_i||^2, nrm[i] = ||emb_i|| ----------------
__global__ void rowstats_kernel(const float* __restrict__ theta,
                                const float* __restrict__ emb,
                                float* __restrict__ sq, float* __restrict__ nrm) {
    int row = blockIdx.x;
    int t = threadIdx.x;  // 256 threads == F
    float tv = theta[row * F + t];
    float ev = emb[row * F + t];
    float s1 = tv * tv, s2 = ev * ev;
    for (int off = 32; off; off >>= 1) {
        s1 += __shfl_down(s1, off, 64);
        s2 += __shfl_down(s2, off, 64);
    }
    __shared__ float w1[4], w2[4];
    int wid = t >> 6;
    if ((t & 63) == 0) { w1[wid] = s1; w2[wid] = s2; }
    __syncthreads();
    if (t == 0) {
        sq[row]  = w1[0] + w1[1] + w1[2] + w1[3];
        nrm[row] = sqrtf(w2[0] + w2[1] + w2[2] + w2[3]);
    }
}

// ---------------- Gram GEMM (X @ X^T) + epilogue -> K or Pc ----------------
// z=0: theta -> K = exp(-alpha * max(sq_i + sq_j - 2G, 0))
// z=1: emb   -> Pc = G / (n_i * n_j + EPS)
__global__ __launch_bounds__(256) void gram_kernel(
    const float* __restrict__ theta, const float* __restrict__ emb,
    const float* __restrict__ sq, const float* __restrict__ nrm,
    float* __restrict__ Kg, float* __restrict__ Pc) {
    int z = blockIdx.z;
    const float* X = (z == 0) ? theta : emb;
    int bi = blockIdx.y * 64;
    int bj = blockIdx.x * 64;
    __shared__ float sA[16][65];  // [k][i]
    __shared__ float sB[16][65];  // [k][j]
    int tid = threadIdx.x;
    int tx = tid & 15, ty = tid >> 4;
    float acc[4][4] = {};
    int lr = tid >> 2;            // 0..63 row within tile
    int lk = (tid & 3) * 4;       // 0,4,8,12

    for (int k0 = 0; k0 < F; k0 += 16) {
        float4 va = *(const float4*)&X[(size_t)(bi + lr) * F + k0 + lk];
        float4 vb = *(const float4*)&X[(size_t)(bj + lr) * F + k0 + lk];
        sA[lk + 0][lr] = va.x; sA[lk + 1][lr] = va.y; sA[lk + 2][lr] = va.z; sA[lk + 3][lr] = va.w;
        sB[lk + 0][lr] = vb.x; sB[lk + 1][lr] = vb.y; sB[lk + 2][lr] = vb.z; sB[lk + 3][lr] = vb.w;
        __syncthreads();
#pragma unroll
        for (int kk = 0; kk < 16; kk++) {
            float a0[4], b0[4];
#pragma unroll
            for (int i = 0; i < 4; i++) a0[i] = sA[kk][ty * 4 + i];
#pragma unroll
            for (int j = 0; j < 4; j++) b0[j] = sB[kk][tx * 4 + j];
#pragma unroll
            for (int i = 0; i < 4; i++)
#pragma unroll
                for (int j = 0; j < 4; j++) acc[i][j] = fmaf(a0[i], b0[j], acc[i][j]);
        }
        __syncthreads();
    }
#pragma unroll
    for (int i = 0; i < 4; i++) {
        int gi = bi + ty * 4 + i;
        int gj = bj + tx * 4;
        float4 o;
        if (z == 0) {
            float si = sq[gi];
            float c0 = fmaxf(si + sq[gj + 0] - 2.0f * acc[i][0], 0.0f);
            float c1 = fmaxf(si + sq[gj + 1] - 2.0f * acc[i][1], 0.0f);
            float c2 = fmaxf(si + sq[gj + 2] - 2.0f * acc[i][2], 0.0f);
            float c3 = fmaxf(si + sq[gj + 3] - 2.0f * acc[i][3], 0.0f);
            o.x = expf(-ALPHA * c0); o.y = expf(-ALPHA * c1);
            o.z = expf(-ALPHA * c2); o.w = expf(-ALPHA * c3);
            *(float4*)&Kg[(size_t)gi * D + gj] = o;
        } else {
            float ni = nrm[gi];
            o.x = acc[i][0] / (ni * nrm[gj + 0] + EPSV);
            o.y = acc[i][1] / (ni * nrm[gj + 1] + EPSV);
            o.z = acc[i][2] / (ni * nrm[gj + 2] + EPSV);
            o.w = acc[i][3] / (ni * nrm[gj + 3] + EPSV);
            *(float4*)&Pc[(size_t)gi * D + gj] = o;
        }
    }
}

// ---------------- row sums of Pc -> invr[i] = 1 / sum_j Pc[i][j] ----------------
__global__ void rowsum_kernel(const float* __restrict__ Pc, float* __restrict__ invr) {
    int row = blockIdx.x;
    int t = threadIdx.x;
    float s = 0.0f;
    const float4* p4 = (const float4*)(Pc + (size_t)row * D);
    for (int k = t; k < D / 4; k += 256) {
        float4 v = p4[k];
        s += v.x + v.y + v.z + v.w;
    }
    for (int off = 32; off; off >>= 1) s += __shfl_down(s, off, 64);
    __shared__ float w[4];
    if ((t & 63) == 0) w[t >> 6] = s;
    __syncthreads();
    if (t == 0) invr[row] = 1.0f / (w[0] + w[1] + w[2] + w[3]);
}

// ---------------- persistent cooperative Sinkhorn + KL ----------------
__global__ __launch_bounds__(256) void sinkhorn_kernel(
    const float* __restrict__ Kg, const float* __restrict__ Pc,
    const float* __restrict__ invr,
    float* __restrict__ u_g, float* __restrict__ v_g,
    float* __restrict__ err_buf,  // [10]
    float* __restrict__ S_buf,    // [1]
    float* __restrict__ kl_buf,   // [1]
    float* __restrict__ out) {
    cg::grid_group grid = cg::this_grid();
    extern __shared__ float Krow[];  // ROWS_PER_BLK * D floats = 64 KB
    int tid = threadIdx.x;
    int blk = blockIdx.x;
    int r = tid >> 5;       // 0..7 local row
    int lane = tid & 31;    // 32 lanes per row
    int row = blk * ROWS_PER_BLK + r;

    if (blk == 0) {
        if (tid < 10) err_buf[tid] = 0.0f;
        if (tid == 10) S_buf[0] = 0.0f;
        if (tid == 11) kl_buf[0] = 0.0f;
    }

    // stage this block's 8 K-rows into LDS (16B vectors)
    {
        const float4* src = (const float4*)(Kg + (size_t)blk * ROWS_PER_BLK * D);
        float4* dst = (float4*)Krow;
        for (int i = tid; i < ROWS_PER_BLK * D / 4; i += 256) dst[i] = src[i];
    }
    __syncthreads();

    const float bval = 1.0f / (float)D;
    const float aval = 1.0f / (float)D;
    const float4* Kr4 = (const float4*)(Krow + r * D);
    const float4* v4 = (const float4*)v_g;
    const float4* u4 = (const float4*)u_g;

    // Ku for u0 = ones: row sum
    float p = 0.0f;
    for (int k = lane; k < D / 4; k += 32) {
        float4 a = Kr4[k];
        p += a.x + a.y + a.z + a.w;
    }
    for (int off = 16; off; off >>= 1) p += __shfl_xor(p, off, 32);
    float Ku = p;

    float err = 1.0f;
    int cpt = 0;
    float v_r = 0.0f, u_r = 0.0f;
    while (err > STOPTHR && cpt < 500) {
        // v = b / (K^T u + eps)  (elementwise on owned rows; K symmetric)
        v_r = bval / (Ku + EPSV);
        if (lane == 0) v_g[row] = v_r;
        grid.sync();
        // u = a / (K v + eps)
        p = 0.0f;
        for (int k = lane; k < D / 4; k += 32) {
            float4 a = Kr4[k];
            float4 b = v4[k];
            p = fmaf(a.x, b.x, p); p = fmaf(a.y, b.y, p);
            p = fmaf(a.z, b.z, p); p = fmaf(a.w, b.w, p);
        }
        for (int off = 16; off; off >>= 1) p += __shfl_xor(p, off, 32);
        u_r = aval / (p + EPSV);
        if (lane == 0) u_g[row] = u_r;
        grid.sync();
        // Ku = K @ u_new (needed for next v; also for err via bb = v .* Ku)
        p = 0.0f;
        for (int k = lane; k < D / 4; k += 32) {
            float4 a = Kr4[k];
            float4 b = u4[k];
            p = fmaf(a.x, b.x, p); p = fmaf(a.y, b.y, p);
            p = fmaf(a.z, b.z, p); p = fmaf(a.w, b.w, p);
        }
        for (int off = 16; off; off >>= 1) p += __shfl_xor(p, off, 32);
        Ku = p;
        cpt++;
        if (cpt % 50 == 1) {
            int chk = cpt / 50;  // 0..9
            float e = fabsf(v_r * Ku - bval);
            if (lane == 0) atomicAdd(&err_buf[chk], e);
            grid.sync();
            err = __hip_atomic_load(&err_buf[chk], __ATOMIC_ACQUIRE, __HIP_MEMORY_SCOPE_AGENT);
        }
    }

    // ---- epilogue: S = sum(max(u_i K_ij v_j, 1e-6)) ----
    float pS = 0.0f;
    for (int k = lane; k < D / 4; k += 32) {
        float4 a = Kr4[k];
        float4 b = v4[k];
        pS += fmaxf(u_r * a.x * b.x, 1e-6f) + fmaxf(u_r * a.y * b.y, 1e-6f) +
              fmaxf(u_r * a.z * b.z, 1e-6f) + fmaxf(u_r * a.w * b.w, 1e-6f);
    }
    for (int off = 16; off; off >>= 1) pS += __shfl_xor(pS, off, 32);
    if (lane == 0) atomicAdd(S_buf, pS);
    grid.sync();
    float S = __hip_atomic_load(S_buf, __ATOMIC_ACQUIRE, __HIP_MEMORY_SCOPE_AGENT);
    float logS = logf(S);

    // ---- kl = sum P*(logP - logQ), P = Pc_ij*0.5*(invr_i+invr_j), logQ = log(qc) - logS ----
    float invr_i = invr[row];
    float pkl = 0.0f;
    const float4* Pc4 = (const float4*)(Pc + (size_t)row * D);
    const float4* ir4 = (const float4*)invr;
    for (int k = lane; k < D / 4; k += 32) {
        float4 a = Kr4[k];
        float4 b = v4[k];
        float4 pc = Pc4[k];
        float4 ir = ir4[k];
        float P0 = pc.x * 0.5f * (invr_i + ir.x);
        float P1 = pc.y * 0.5f * (invr_i + ir.y);
        float P2 = pc.z * 0.5f * (invr_i + ir.z);
        float P3 = pc.w * 0.5f * (invr_i + ir.w);
        float q0 = fmaxf(u_r * a.x * b.x, 1e-6f);
        float q1 = fmaxf(u_r * a.y * b.y, 1e-6f);
        float q2 = fmaxf(u_r * a.z * b.z, 1e-6f);
        float q3 = fmaxf(u_r * a.w * b.w, 1e-6f);
        pkl += P0 * (logf(P0) - logf(q0) + logS);
        pkl += P1 * (logf(P1) - logf(q1) + logS);
        pkl += P2 * (logf(P2) - logf(q2) + logS);
        pkl += P3 * (logf(P3) - logf(q3) + logS);
    }
    for (int off = 16; off; off >>= 1) pkl += __shfl_xor(pkl, off, 32);
    if (lane == 0) atomicAdd(kl_buf, pkl);
    grid.sync();
    if (blk == 0 && tid == 0)
        out[0] = __hip_atomic_load(kl_buf, __ATOMIC_ACQUIRE, __HIP_MEMORY_SCOPE_AGENT);
}

extern "C" void kernel_launch(void* const* d_in, const int* in_sizes, int n_in,
                              void* d_out, int out_size, void* d_ws, size_t ws_size,
                              hipStream_t stream) {
    const float* theta = (const float*)d_in[0];
    const float* emb = (const float*)d_in[1];
    float* out = (float*)d_out;

    char* ws = (char*)d_ws;
    float* Kg   = (float*)ws;                       // 16 MiB
    float* Pc   = (float*)(ws + (1u << 24));        // 16 MiB
    char* tail  = ws + (1u << 25);
    float* sq   = (float*)(tail);
    float* nrm  = (float*)(tail + 8192);
    float* invr = (float*)(tail + 16384);
    float* u_g  = (float*)(tail + 24576);
    float* v_g  = (float*)(tail + 32768);
    float* err_buf = (float*)(tail + 40960);        // 10 floats
    float* S_buf   = (float*)(tail + 41216);
    float* kl_buf  = (float*)(tail + 41472);

    rowstats_kernel<<<D, 256, 0, stream>>>(theta, emb, sq, nrm);
    gram_kernel<<<dim3(32, 32, 2), 256, 0, stream>>>(theta, emb, sq, nrm, Kg, Pc);
    rowsum_kernel<<<D, 256, 0, stream>>>(Pc, invr);

    void* args[] = {(void*)&Kg, (void*)&Pc, (void*)&invr, (void*)&u_g, (void*)&v_g,
                    (void*)&err_buf, (void*)&S_buf, (void*)&kl_buf, (void*)&out};
    hipLaunchCooperativeKernel((void*)sinkhorn_kernel, dim3(NBLK), dim3(256), args,
                               ROWS_PER_BLK * D * sizeof(float), stream);
}

// Round 2
// 269.737 us; speedup vs baseline: 1.2847x; 1.2847x over previous
//
#include <hip/hip_runtime.h>
#include <math.h>

#define D 2048
#define F 256
#define ALPHA 0.005f
#define STOPTHR 0.005f
#define EPSV 1e-16f
#define RPB 8
#define NBLK (D / RPB)  // 256 blocks, 1 per CU

// ---- hand-rolled grid barrier: monotonic generation, single counter ----
__device__ __forceinline__ void gbar(unsigned* cnt, unsigned* gen, unsigned& lg) {
    __syncthreads();
    if (threadIdx.x == 0) {
        unsigned g = lg;
        unsigned a = __hip_atomic_fetch_add(cnt, 1u, __ATOMIC_ACQ_REL, __HIP_MEMORY_SCOPE_AGENT);
        if (a == NBLK - 1) {
            __hip_atomic_store(cnt, 0u, __ATOMIC_RELAXED, __HIP_MEMORY_SCOPE_AGENT);
            __hip_atomic_store(gen, g + 1u, __ATOMIC_RELEASE, __HIP_MEMORY_SCOPE_AGENT);
        } else {
            // poll while gen < g+1 (wrap-safe signed compare)
            while ((int)(__hip_atomic_load(gen, __ATOMIC_ACQUIRE, __HIP_MEMORY_SCOPE_AGENT) - (g + 1u)) < 0) {}
        }
    }
    __syncthreads();
    lg++;
}

// ---------------- row stats + flag init ----------------
__global__ void rowstats_kernel(const float* __restrict__ theta,
                                const float* __restrict__ emb,
                                float* __restrict__ sq, float* __restrict__ nrm,
                                float* __restrict__ err_buf, float* __restrict__ S_buf,
                                float* __restrict__ kl_buf,
                                unsigned* __restrict__ bar_cnt, unsigned* __restrict__ bar_gen) {
    if (blockIdx.x == 0) {
        int t = threadIdx.x;
        if (t < 10) err_buf[t] = 0.0f;
        else if (t == 10) S_buf[0] = 0.0f;
        else if (t == 11) kl_buf[0] = 0.0f;
        else if (t == 12) *bar_cnt = 0u;
        else if (t == 13) *bar_gen = 0u;
    }
    int row = blockIdx.x;
    int t = threadIdx.x;  // 256 threads == F
    float tv = theta[row * F + t];
    float ev = emb[row * F + t];
    float s1 = tv * tv, s2 = ev * ev;
    for (int off = 32; off; off >>= 1) {
        s1 += __shfl_down(s1, off, 64);
        s2 += __shfl_down(s2, off, 64);
    }
    __shared__ float w1[4], w2[4];
    int wid = t >> 6;
    if ((t & 63) == 0) { w1[wid] = s1; w2[wid] = s2; }
    __syncthreads();
    if (t == 0) {
        sq[row]  = w1[0] + w1[1] + w1[2] + w1[3];
        nrm[row] = sqrtf(w2[0] + w2[1] + w2[2] + w2[3]);
    }
}

// ---------------- Gram GEMM 128x128 tile, 8x8 micro-tile, dbuf LDS ----------------
__global__ __launch_bounds__(256) void gram_kernel(
    const float* __restrict__ theta, const float* __restrict__ emb,
    const float* __restrict__ sq, const float* __restrict__ nrm,
    float* __restrict__ Kg, float* __restrict__ Pc) {
    int z = blockIdx.z;
    const float* X = (z == 0) ? theta : emb;
    int bi = blockIdx.y * 128;
    int bj = blockIdx.x * 128;
    __shared__ float sA[2][16][132];  // [buf][k][i], pad 132 keeps 16B align + 2-way banks
    __shared__ float sB[2][16][132];
    int tid = threadIdx.x;
    int tx = tid & 15, ty = tid >> 4;
    int srow = tid >> 2;           // 0..63
    int skq = (tid & 3) * 4;       // 0,4,8,12
    float acc[8][8] = {};

    auto stage = [&](int bufi, int k0) {
        float4 va  = *(const float4*)&X[(size_t)(bi + srow) * F + k0 + skq];
        float4 vb  = *(const float4*)&X[(size_t)(bj + srow) * F + k0 + skq];
        float4 va2 = *(const float4*)&X[(size_t)(bi + 64 + srow) * F + k0 + skq];
        float4 vb2 = *(const float4*)&X[(size_t)(bj + 64 + srow) * F + k0 + skq];
        sA[bufi][skq + 0][srow] = va.x;  sA[bufi][skq + 1][srow] = va.y;
        sA[bufi][skq + 2][srow] = va.z;  sA[bufi][skq + 3][srow] = va.w;
        sA[bufi][skq + 0][64 + srow] = va2.x; sA[bufi][skq + 1][64 + srow] = va2.y;
        sA[bufi][skq + 2][64 + srow] = va2.z; sA[bufi][skq + 3][64 + srow] = va2.w;
        sB[bufi][skq + 0][srow] = vb.x;  sB[bufi][skq + 1][srow] = vb.y;
        sB[bufi][skq + 2][srow] = vb.z;  sB[bufi][skq + 3][srow] = vb.w;
        sB[bufi][skq + 0][64 + srow] = vb2.x; sB[bufi][skq + 1][64 + srow] = vb2.y;
        sB[bufi][skq + 2][64 + srow] = vb2.z; sB[bufi][skq + 3][64 + srow] = vb2.w;
    };

    stage(0, 0);
    __syncthreads();
    for (int s = 0; s < 16; s++) {
        int bufi = s & 1;
        if (s < 15) stage(bufi ^ 1, (s + 1) * 16);
#pragma unroll
        for (int kk = 0; kk < 16; kk++) {
            float4 a0 = *(const float4*)&sA[bufi][kk][ty * 8];
            float4 a1 = *(const float4*)&sA[bufi][kk][ty * 8 + 4];
            float4 b0 = *(const float4*)&sB[bufi][kk][tx * 8];
            float4 b1 = *(const float4*)&sB[bufi][kk][tx * 8 + 4];
            float a[8] = {a0.x, a0.y, a0.z, a0.w, a1.x, a1.y, a1.z, a1.w};
            float b[8] = {b0.x, b0.y, b0.z, b0.w, b1.x, b1.y, b1.z, b1.w};
#pragma unroll
            for (int i = 0; i < 8; i++)
#pragma unroll
                for (int j = 0; j < 8; j++) acc[i][j] = fmaf(a[i], b[j], acc[i][j]);
        }
        __syncthreads();
    }

    if (z == 0) {
        float sqj[8];
#pragma unroll
        for (int c = 0; c < 8; c++) sqj[c] = sq[bj + tx * 8 + c];
#pragma unroll
        for (int i = 0; i < 8; i++) {
            int gi = bi + ty * 8 + i;
            float si = sq[gi];
            float o[8];
#pragma unroll
            for (int c = 0; c < 8; c++) {
                float cc = fmaxf(si + sqj[c] - 2.0f * acc[i][c], 0.0f);
                o[c] = __expf(-ALPHA * cc);
            }
            *(float4*)&Kg[(size_t)gi * D + bj + tx * 8]     = make_float4(o[0], o[1], o[2], o[3]);
            *(float4*)&Kg[(size_t)gi * D + bj + tx * 8 + 4] = make_float4(o[4], o[5], o[6], o[7]);
        }
    } else {
        float nrmj[8];
#pragma unroll
        for (int c = 0; c < 8; c++) nrmj[c] = nrm[bj + tx * 8 + c];
#pragma unroll
        for (int i = 0; i < 8; i++) {
            int gi = bi + ty * 8 + i;
            float ni = nrm[gi];
            float o[8];
#pragma unroll
            for (int c = 0; c < 8; c++) o[c] = acc[i][c] / (ni * nrmj[c] + EPSV);
            *(float4*)&Pc[(size_t)gi * D + bj + tx * 8]     = make_float4(o[0], o[1], o[2], o[3]);
            *(float4*)&Pc[(size_t)gi * D + bj + tx * 8 + 4] = make_float4(o[4], o[5], o[6], o[7]);
        }
    }
}

// ---------------- persistent Sinkhorn + fused rowsum + KL ----------------
__global__ __launch_bounds__(256) void sinkhorn_kernel(
    const float* __restrict__ Kg, const float* __restrict__ Pc,
    float* __restrict__ rsum,
    float* __restrict__ u_g, float* __restrict__ v_g,
    float* __restrict__ err_buf, float* __restrict__ S_buf, float* __restrict__ kl_buf,
    unsigned* __restrict__ bar_cnt, unsigned* __restrict__ bar_gen,
    float* __restrict__ out) {
    extern __shared__ float Krow[];  // RPB * D floats = 64 KB
    int tid = threadIdx.x;
    int blk = blockIdx.x;
    int r = tid >> 5;
    int lane = tid & 31;
    int row = blk * RPB + r;
    unsigned lg = 0;

    // stage this block's 8 K-rows into LDS
    {
        const float4* src = (const float4*)(Kg + (size_t)blk * RPB * D);
        float4* dst = (float4*)Krow;
        for (int i = tid; i < RPB * D / 4; i += 256) dst[i] = src[i];
    }
    // fused rowsum of Pc for this block's rows
    {
        const float4* p4 = (const float4*)(Pc + (size_t)row * D);
        float s = 0.0f;
        for (int k = lane; k < D / 4; k += 32) {
            float4 v = p4[k];
            s += (v.x + v.y) + (v.z + v.w);
        }
#pragma unroll
        for (int off = 16; off; off >>= 1) s += __shfl_xor(s, off, 32);
        if (lane == 0) rsum[row] = s;  // published at first gbar
    }
    __syncthreads();

    const float bval = 1.0f / (float)D;
    const float aval = 1.0f / (float)D;
    const float4* Kr4 = (const float4*)(Krow + r * D);
    const float4* v4 = (const float4*)v_g;
    const float4* u4 = (const float4*)u_g;

    // Ku for u0 = ones: row sum
    float p = 0.0f;
    for (int k = lane; k < D / 4; k += 32) {
        float4 a = Kr4[k];
        p += (a.x + a.y) + (a.z + a.w);
    }
#pragma unroll
    for (int off = 16; off; off >>= 1) p += __shfl_xor(p, off, 32);
    float Ku = p;

    float err = 1.0f;
    int cpt = 0;
    float v_r = 0.0f, u_r = 0.0f;
    while (err > STOPTHR && cpt < 500) {
        v_r = bval / (Ku + EPSV);
        if (lane == 0) v_g[row] = v_r;
        gbar(bar_cnt, bar_gen, lg);
        p = 0.0f;
        for (int k = lane; k < D / 4; k += 32) {
            float4 a = Kr4[k];
            float4 b = v4[k];
            p = fmaf(a.x, b.x, p); p = fmaf(a.y, b.y, p);
            p = fmaf(a.z, b.z, p); p = fmaf(a.w, b.w, p);
        }
#pragma unroll
        for (int off = 16; off; off >>= 1) p += __shfl_xor(p, off, 32);
        u_r = aval / (p + EPSV);
        if (lane == 0) u_g[row] = u_r;
        gbar(bar_cnt, bar_gen, lg);
        p = 0.0f;
        for (int k = lane; k < D / 4; k += 32) {
            float4 a = Kr4[k];
            float4 b = u4[k];
            p = fmaf(a.x, b.x, p); p = fmaf(a.y, b.y, p);
            p = fmaf(a.z, b.z, p); p = fmaf(a.w, b.w, p);
        }
#pragma unroll
        for (int off = 16; off; off >>= 1) p += __shfl_xor(p, off, 32);
        Ku = p;
        cpt++;
        if (cpt % 50 == 1) {
            int chk = cpt / 50;  // 0..9
            float e = fabsf(v_r * Ku - bval);   // uniform across the row's 32 lanes
            e += __shfl_xor(e, 32, 64);         // pair the wave's two rows
            if ((tid & 63) == 0) atomicAdd(&err_buf[chk], e);
            gbar(bar_cnt, bar_gen, lg);
            err = err_buf[chk];
        }
    }

    // ---- S = sum(max(u_i K_ij v_j, 1e-6)) ----
    float pS = 0.0f;
    for (int k = lane; k < D / 4; k += 32) {
        float4 a = Kr4[k];
        float4 b = v4[k];
        pS += fmaxf(u_r * a.x * b.x, 1e-6f) + fmaxf(u_r * a.y * b.y, 1e-6f) +
              fmaxf(u_r * a.z * b.z, 1e-6f) + fmaxf(u_r * a.w * b.w, 1e-6f);
    }
#pragma unroll
    for (int off = 16; off; off >>= 1) pS += __shfl_xor(pS, off, 32);
    pS += __shfl_xor(pS, 32, 64);
    if ((tid & 63) == 0) atomicAdd(S_buf, pS);
    gbar(bar_cnt, bar_gen, lg);
    float logS = __logf(S_buf[0]);

    // ---- kl = sum P*(logP - logQc + logS), P = Pc_ij*0.5*(1/r_i + 1/r_j) ----
    float invr_i = 1.0f / rsum[row];
    float pkl = 0.0f;
    const float4* Pc4 = (const float4*)(Pc + (size_t)row * D);
    const float4* rs4 = (const float4*)rsum;
    for (int k = lane; k < D / 4; k += 32) {
        float4 a = Kr4[k];
        float4 b = v4[k];
        float4 pc = Pc4[k];
        float4 rs = rs4[k];
        float P0 = pc.x * 0.5f * (invr_i + 1.0f / rs.x);
        float P1 = pc.y * 0.5f * (invr_i + 1.0f / rs.y);
        float P2 = pc.z * 0.5f * (invr_i + 1.0f / rs.z);
        float P3 = pc.w * 0.5f * (invr_i + 1.0f / rs.w);
        float q0 = fmaxf(u_r * a.x * b.x, 1e-6f);
        float q1 = fmaxf(u_r * a.y * b.y, 1e-6f);
        float q2 = fmaxf(u_r * a.z * b.z, 1e-6f);
        float q3 = fmaxf(u_r * a.w * b.w, 1e-6f);
        pkl += P0 * (__logf(P0) - __logf(q0) + logS);
        pkl += P1 * (__logf(P1) - __logf(q1) + logS);
        pkl += P2 * (__logf(P2) - __logf(q2) + logS);
        pkl += P3 * (__logf(P3) - __logf(q3) + logS);
    }
#pragma unroll
    for (int off = 16; off; off >>= 1) pkl += __shfl_xor(pkl, off, 32);
    pkl += __shfl_xor(pkl, 32, 64);
    if ((tid & 63) == 0) atomicAdd(kl_buf, pkl);
    gbar(bar_cnt, bar_gen, lg);
    if (blk == 0 && tid == 0) out[0] = kl_buf[0];
}

extern "C" void kernel_launch(void* const* d_in, const int* in_sizes, int n_in,
                              void* d_out, int out_size, void* d_ws, size_t ws_size,
                              hipStream_t stream) {
    const float* theta = (const float*)d_in[0];
    const float* emb = (const float*)d_in[1];
    float* out = (float*)d_out;

    char* ws = (char*)d_ws;
    float* Kg = (float*)ws;                      // 16 MiB
    float* Pc = (float*)(ws + (1u << 24));       // 16 MiB
    char* tail = ws + (1u << 25);
    float* sq   = (float*)(tail);
    float* nrm  = (float*)(tail + 8192);
    float* rsum = (float*)(tail + 16384);
    float* u_g  = (float*)(tail + 24576);
    float* v_g  = (float*)(tail + 32768);
    float* err_buf = (float*)(tail + 40960);     // 10 floats
    float* S_buf   = (float*)(tail + 41216);
    float* kl_buf  = (float*)(tail + 41472);
    unsigned* bar_cnt = (unsigned*)(tail + 41728);
    unsigned* bar_gen = (unsigned*)(tail + 41984);

    rowstats_kernel<<<D, 256, 0, stream>>>(theta, emb, sq, nrm, err_buf, S_buf, kl_buf,
                                           bar_cnt, bar_gen);
    gram_kernel<<<dim3(16, 16, 2), 256, 0, stream>>>(theta, emb, sq, nrm, Kg, Pc);

    void* args[] = {(void*)&Kg, (void*)&Pc, (void*)&rsum, (void*)&u_g, (void*)&v_g,
                    (void*)&err_buf, (void*)&S_buf, (void*)&kl_buf,
                    (void*)&bar_cnt, (void*)&bar_gen, (void*)&out};
    hipLaunchCooperativeKernel((void*)sinkhorn_kernel, dim3(NBLK), dim3(256), args,
                               RPB * D * sizeof(float), stream);
}